// Round 3
// baseline (482.657 us; speedup 1.0000x reference)
//
#include <hip/hip_runtime.h>

#define B_SZ 16
#define N_SZ 8192
#define D_SZ 384
#define KN_SZ 16
#define K_SZ 8
#define H_SZ 128
#define M_TOTAL (B_SZ * N_SZ)   // 131072 nodes
#define KSTEPS 12               // 384 / 32
#define TROWS 32                // GEMM tile rows
#define NT (M_TOTAL / TROWS)    // 4096 tiles
#define LDSA_STRIDE 400         // bf16 elems; 200 dw == 8 mod 32 -> 4-way max on b128 read
#define HTS 132                 // fp32 stride of htile; 132 dw == 4 mod 32 -> <=2-way
#define GEMM_GRID 512

typedef short short8 __attribute__((ext_vector_type(8)));
typedef short short4v __attribute__((ext_vector_type(4)));
typedef float floatx4 __attribute__((ext_vector_type(4)));

__device__ __forceinline__ unsigned short f2bf(float f) {
    unsigned u = __builtin_bit_cast(unsigned, f);
    u += 0x7FFFu + ((u >> 16) & 1u);   // round-to-nearest-even
    return (unsigned short)(u >> 16);
}
__device__ __forceinline__ float bf2f(unsigned short b) {
    unsigned u = ((unsigned)b) << 16;
    return __builtin_bit_cast(float, u);
}

// ---------------------------------------------------------------------------
// PREP: blocks 0..383 build swizzled fused weights; block 384 zeroes norms;
// blocks 385..400 per-batch q contributions (+layer-1 biases), exact fp32.
// wswz: flat = ((ct*12+s)*64 + lane)*8 + j <-> B[k=s*32+(lane>>4)*8+j][n=ct*16+(lane&15)]
// ---------------------------------------------------------------------------
__global__ void prep_kernel(const float* __restrict__ q_embs,
                            const float* __restrict__ coin_w1,
                            const float* __restrict__ coin_b1,
                            const float* __restrict__ path_w1,
                            const float* __restrict__ path_b1,
                            unsigned short* __restrict__ wswz,
                            float* __restrict__ qcoin, float* __restrict__ qpath,
                            float* __restrict__ norms) {
    int blk = blockIdx.x;
    int t = threadIdx.x;
    if (blk < 384) {
        int f = blk * 256 + t;                   // 98304 total
        int j  = f & 7;
        int l  = (f >> 3) & 63;
        int ss = (f >> 9) % KSTEPS;
        int ct = f / (KSTEPS * 512);
        int k = ss * 32 + ((l >> 4) << 3) + j;
        int n = ct * 16 + (l & 15);
        float v = (n < H_SZ) ? coin_w1[k * H_SZ + n]
                             : path_w1[k * H_SZ + (n - H_SZ)];
        wswz[f] = f2bf(v);
    } else if (blk == 384) {
        if (t < B_SZ) norms[t] = 0.f;
    } else {
        int b = blk - 385;
        const float* q = q_embs + b * D_SZ;
        if (t < H_SZ) {
            float acc = coin_b1[t];
            for (int d = 0; d < D_SZ; d++)
                acc += q[d] * coin_w1[(D_SZ + d) * H_SZ + t];
            qcoin[b * H_SZ + t] = acc;
        } else if (t < 2 * H_SZ) {
            int h = t - H_SZ;
            float acc = path_b1[h];
            for (int d = 0; d < D_SZ; d++)
                acc += q[d] * path_w1[(D_SZ + K_SZ + d) * H_SZ + h];
            qpath[b * H_SZ + h] = acc;
        }
    }
}

// ---------------------------------------------------------------------------
// GEMM + fused amps epilogue.
// H[131072 x 256] = sent(bf16) @ Wfused(bf16), 32-row tiles, 4 waves.
// Wave w owns cols [64w,64w+64) (bfrag resident, 192 VGPRs).
//   waves 0,1 (hcoin cols): acc -> fp32 LDS htile
//   waves 2,3 (hpath cols): acc -> bf16 global, blocked hB[mt16*2048+col*16+row16]
// Then all 256 threads: amps[m] = relu(htile+qcoin)@w2 + b2 ; z0 = amps/256.
// ---------------------------------------------------------------------------
__global__ __launch_bounds__(256, 2)
void gemm_fused(const float* __restrict__ sent,
                const unsigned short* __restrict__ wswz,
                const float* __restrict__ qcoin,
                const float* __restrict__ coin_w2,
                const float* __restrict__ coin_b2,
                unsigned short* __restrict__ hpathB,
                float* __restrict__ amps,
                float* __restrict__ z0) {
    __shared__ short als[TROWS * LDSA_STRIDE];   // 25600 B
    __shared__ float htile[TROWS * HTS];         // 16896 B
    __shared__ float w2s[H_SZ * K_SZ];           // 4096 B
    __shared__ float qcs[H_SZ];                  // 512 B
    __shared__ float b2s[K_SZ];                  // 32 B
    const int tid = threadIdx.x;
    const int wave = tid >> 6, lane = tid & 63;
    const int m_lane = lane & 15, quad = lane >> 4;

    for (int i = tid; i < H_SZ * K_SZ; i += 256) w2s[i] = coin_w2[i];
    if (tid < K_SZ) b2s[tid] = coin_b2[tid];

    // resident B fragments for this wave's 4 col-tiles
    short8 bfrag[4][KSTEPS];
#pragma unroll
    for (int c = 0; c < 4; c++) {
        int ct = wave * 4 + c;
#pragma unroll
        for (int s = 0; s < KSTEPS; s++)
            bfrag[c][s] = *(const short8*)(wswz + ((((ct * KSTEPS + s) * 64) + lane) << 3));
    }

    const int colw = (wave & 1) * 64;
    const int is_path = (wave >= 2);

    for (int mt = blockIdx.x; mt < NT; mt += GEMM_GRID) {
        const int b = mt >> 8;                   // 256 tiles per batch
        // stage A: 32 rows x 384 fp32 -> bf16 LDS; 12 float4 per thread
        const float* abase = sent + (size_t)mt * TROWS * D_SZ;
#pragma unroll
        for (int cc = 0; cc < 3; cc++) {
            float4 v[4];
#pragma unroll
            for (int u = 0; u < 4; u++)
                v[u] = *(const float4*)(abase + (size_t)((cc * 4 + u) * 256 + tid) * 4);
#pragma unroll
            for (int u = 0; u < 4; u++) {
                int e4 = (cc * 4 + u) * 256 + tid;
                int row = e4 / 96;               // 96 float4 per row
                int c4  = e4 - row * 96;
                short4v sv;
                sv.x = (short)f2bf(v[u].x); sv.y = (short)f2bf(v[u].y);
                sv.z = (short)f2bf(v[u].z); sv.w = (short)f2bf(v[u].w);
                *(short4v*)&als[row * LDSA_STRIDE + c4 * 4] = sv;
            }
        }
        if (tid < H_SZ) qcs[tid] = qcoin[b * H_SZ + tid];
        __syncthreads();

#pragma unroll
        for (int rt = 0; rt < 2; rt++) {
            floatx4 acc[4];
#pragma unroll
            for (int c = 0; c < 4; c++) acc[c] = (floatx4){0.f, 0.f, 0.f, 0.f};
#pragma unroll
            for (int s = 0; s < KSTEPS; s++) {
                short8 afrag = *(const short8*)&als[(rt * 16 + m_lane) * LDSA_STRIDE + s * 32 + quad * 8];
#pragma unroll
                for (int c = 0; c < 4; c++)
                    acc[c] = __builtin_amdgcn_mfma_f32_16x16x32_bf16(afrag, bfrag[c][s], acc[c], 0, 0, 0);
            }
            if (!is_path) {
                // hcoin: fp32 acc -> LDS htile (scalar stores, <=2-way conflicts)
#pragma unroll
                for (int c = 0; c < 4; c++) {
                    int col = colw + c * 16 + m_lane;
#pragma unroll
                    for (int r = 0; r < 4; r++)
                        htile[(rt * 16 + quad * 4 + r) * HTS + col] = acc[c][r];
                }
            } else {
                // hpath: bf16 global, blocked layout; one 8B store per col-tile
                int mt16 = mt * 2 + rt;
#pragma unroll
                for (int c = 0; c < 4; c++) {
                    int col = colw + c * 16 + m_lane;
                    short4v sv;
                    sv.x = (short)f2bf(acc[c][0]); sv.y = (short)f2bf(acc[c][1]);
                    sv.z = (short)f2bf(acc[c][2]); sv.w = (short)f2bf(acc[c][3]);
                    *(short4v*)(hpathB + (size_t)mt16 * 2048 + col * 16 + quad * 4) = sv;
                }
            }
        }
        __syncthreads();

        // amps phase: thread = (row = tid>>3, hg = tid&7); h = hg + 8k, k<16
        {
            const int row = tid >> 3, hg = tid & 7;
            float pa[K_SZ];
#pragma unroll
            for (int j = 0; j < K_SZ; j++) pa[j] = 0.f;
#pragma unroll
            for (int k = 0; k < 16; k++) {
                int h = hg + 8 * k;
                float hv = htile[row * HTS + h] + qcs[h];
                hv = hv > 0.f ? hv : 0.f;
                float4 wa = *(const float4*)&w2s[h * 8];
                float4 wb = *(const float4*)&w2s[h * 8 + 4];
                pa[0] += hv * wa.x; pa[1] += hv * wa.y; pa[2] += hv * wa.z; pa[3] += hv * wa.w;
                pa[4] += hv * wb.x; pa[5] += hv * wb.y; pa[6] += hv * wb.z; pa[7] += hv * wb.w;
            }
#pragma unroll
            for (int o = 1; o < 8; o <<= 1) {
#pragma unroll
                for (int j = 0; j < K_SZ; j++) pa[j] += __shfl_xor(pa[j], o);
            }
            if ((tid & 7) == 0) {
                const float c0 = 1.0f / 256.0f;  // 1/sqrt(N*K)
                int m = mt * TROWS + row;
#pragma unroll
                for (int j = 0; j < K_SZ; j++) pa[j] += b2s[j];
                float4 o0 = {pa[0], pa[1], pa[2], pa[3]};
                float4 o1 = {pa[4], pa[5], pa[6], pa[7]};
                *(float4*)(amps + (size_t)m * 8)     = o0;
                *(float4*)(amps + (size_t)m * 8 + 4) = o1;
                float4 s0 = {pa[0]*c0, pa[1]*c0, pa[2]*c0, pa[3]*c0};
                float4 s1 = {pa[4]*c0, pa[5]*c0, pa[6]*c0, pa[7]*c0};
                *(float4*)(z0 + (size_t)m * 8)     = s0;
                *(float4*)(z0 + (size_t)m * 8 + 4) = s1;
            }
        }
        __syncthreads();
    }
}

// ---------------------------------------------------------------------------
// walk step (un-normalized; intermediate norms cancel algebraically):
//   v = z[m] + sum_valid z[nbr]
//   last==0:  out[m] = v * amps[m]
//   last==1:  out[m] = v ; atomically accumulate ssq into norms[b]
// 2 threads per node (half-split) for latency hiding.
// ---------------------------------------------------------------------------
__global__ __launch_bounds__(256)
void walk_step(const float* __restrict__ z,
               const int* __restrict__ neighbors,
               const float* __restrict__ amps,
               float* __restrict__ outz,
               float* __restrict__ norms, int last) {
    const int g = blockIdx.x * 256 + threadIdx.x;    // 262144 threads
    const int m = g >> 1, half = g & 1;
    const int b = m >> 13;
    const size_t nbase = (size_t)b << 13;
    const int off = half * 4;

    float4 v = *(const float4*)(z + (size_t)m * 8 + off);
    int nbr[KN_SZ];
    const int4* nb4 = (const int4*)(neighbors + (size_t)m * KN_SZ);
#pragma unroll
    for (int i = 0; i < 4; i++) *(int4*)&nbr[i * 4] = nb4[i];
#pragma unroll
    for (int i = 0; i < KN_SZ; i++) {
        int nn = nbr[i];
        if (nn >= 0 && nn < N_SZ) {
            float4 gv = *(const float4*)(z + (nbase + nn) * 8 + off);
            v.x += gv.x; v.y += gv.y; v.z += gv.z; v.w += gv.w;
        }
    }
    if (!last) {
        float4 a = *(const float4*)(amps + (size_t)m * 8 + off);
        v.x *= a.x; v.y *= a.y; v.z *= a.z; v.w *= a.w;
        *(float4*)(outz + (size_t)m * 8 + off) = v;
    } else {
        *(float4*)(outz + (size_t)m * 8 + off) = v;
        float ss = v.x * v.x + v.y * v.y + v.z * v.z + v.w * v.w;
#pragma unroll
        for (int o = 32; o > 0; o >>= 1) ss += __shfl_down(ss, o);
        __shared__ float blocksum;
        if (threadIdx.x == 0) blocksum = 0.f;
        __syncthreads();
        if ((threadIdx.x & 63) == 0) atomicAdd(&blocksum, ss);
        __syncthreads();
        if (threadIdx.x == 0) atomicAdd(&norms[b], blocksum);
    }
}

// ---------------------------------------------------------------------------
// logits[m] = relu(hpath[m] + qpath[b] + state @ w1_state) @ path_w2 + path_b2
// state = u2[m] * rsqrt(norms[b])  (final normalize, guarded)
// ---------------------------------------------------------------------------
__global__ __launch_bounds__(256)
void logits_kernel(const unsigned short* __restrict__ hpathB,
                   const float* __restrict__ qpath,
                   const float* __restrict__ u2,
                   const float* __restrict__ norms,
                   const float* __restrict__ path_w1,
                   const float* __restrict__ path_w2,
                   const float* __restrict__ path_b2,
                   float* __restrict__ out) {
    __shared__ float w1t[H_SZ * K_SZ];   // w1t[h*8+j] = path_w1[(384+j)*128 + h]
    __shared__ float w2s[H_SZ];
    __shared__ float qps[H_SZ];
    const int tid = threadIdx.x;
    const int m = blockIdx.x * 256 + tid;
    const int b = (blockIdx.x * 256) >> 13;      // block-uniform
    for (int i = tid; i < K_SZ * H_SZ; i += 256) {
        int h = i >> 3, j = i & 7;
        w1t[i] = path_w1[(D_SZ + j) * H_SZ + h];
    }
    if (tid < H_SZ) { w2s[tid] = path_w2[tid]; qps[tid] = qpath[b * H_SZ + tid]; }
    __syncthreads();

    float ssq = norms[b];
    float inv = ssq > 0.f ? rsqrtf(ssq) : 1.0f;
    float st[K_SZ];
    {
        float4 s0 = *(const float4*)(u2 + (size_t)m * 8);
        float4 s1 = *(const float4*)(u2 + (size_t)m * 8 + 4);
        st[0] = s0.x * inv; st[1] = s0.y * inv; st[2] = s0.z * inv; st[3] = s0.w * inv;
        st[4] = s1.x * inv; st[5] = s1.y * inv; st[6] = s1.z * inv; st[7] = s1.w * inv;
    }

    const unsigned short* hb = hpathB + (size_t)(m >> 4) * 2048 + (m & 15);
    float acc = path_b2[0];
    for (int h = 0; h < H_SZ; h++) {
        float hv = bf2f(hb[h * 16]) + qps[h];
        float4 wa = *(const float4*)&w1t[h * 8];
        float4 wb = *(const float4*)&w1t[h * 8 + 4];
        hv += st[0]*wa.x + st[1]*wa.y + st[2]*wa.z + st[3]*wa.w
            + st[4]*wb.x + st[5]*wb.y + st[6]*wb.z + st[7]*wb.w;
        hv = hv > 0.f ? hv : 0.f;
        acc += hv * w2s[h];
    }
    out[m] = acc;
}

// ---------------------------------------------------------------------------
extern "C" void kernel_launch(void* const* d_in, const int* in_sizes, int n_in,
                              void* d_out, int out_size, void* d_ws, size_t ws_size,
                              hipStream_t stream) {
    const float* sent      = (const float*)d_in[0];
    const float* q_embs    = (const float*)d_in[1];
    const int*   neighbors = (const int*)d_in[2];
    const float* coin_w1   = (const float*)d_in[3];
    const float* coin_b1   = (const float*)d_in[4];
    const float* coin_w2   = (const float*)d_in[5];
    const float* coin_b2   = (const float*)d_in[6];
    const float* path_w1   = (const float*)d_in[7];
    const float* path_b1   = (const float*)d_in[8];
    const float* path_w2   = (const float*)d_in[9];
    const float* path_b2   = (const float*)d_in[10];
    float* out = (float*)d_out;

    char* ws = (char*)d_ws;
    unsigned short* wswz = (unsigned short*)ws;                   // 196608 B
    float* qcoin = (float*)(ws + 196608);                         // 8192 B
    float* qpath = (float*)(ws + 196608 + 8192);                  // 8192 B
    float* norms = (float*)(ws + 196608 + 16384);                 // 256 B
    unsigned short* hpathB = (unsigned short*)(ws + 213248);      // 33554432 B
    float* amps = (float*)(ws + 213248 + 33554432ull);            // 4 MB
    float* zA   = amps + (size_t)M_TOTAL * K_SZ;                  // 4 MB
    float* zB   = zA   + (size_t)M_TOTAL * K_SZ;                  // 4 MB

    prep_kernel<<<401, 256, 0, stream>>>(q_embs, coin_w1, coin_b1, path_w1, path_b1,
                                         wswz, qcoin, qpath, norms);
    gemm_fused<<<GEMM_GRID, 256, 0, stream>>>(sent, wswz, qcoin, coin_w2, coin_b2,
                                              hpathB, amps, zA);
    walk_step<<<2 * M_TOTAL / 256, 256, 0, stream>>>(zA, neighbors, amps, zB, norms, 0);
    walk_step<<<2 * M_TOTAL / 256, 256, 0, stream>>>(zB, neighbors, amps, zA, norms, 0);
    walk_step<<<2 * M_TOTAL / 256, 256, 0, stream>>>(zA, neighbors, amps, zB, norms, 1);
    logits_kernel<<<M_TOTAL / 256, 256, 0, stream>>>(hpathB, qpath, zB, norms,
                                                     path_w1, path_w2, path_b2, out);
}

// Round 4
// 458.695 us; speedup vs baseline: 1.0522x; 1.0522x over previous
//
#include <hip/hip_runtime.h>

#define B_SZ 16
#define N_SZ 8192
#define D_SZ 384
#define KN_SZ 16
#define K_SZ 8
#define H_SZ 128
#define M_TOTAL (B_SZ * N_SZ)   // 131072 nodes
#define KSTEPS 12               // 384 / 32
#define MT64 (M_TOTAL / 64)     // 2048 64-row tiles

typedef short short8 __attribute__((ext_vector_type(8)));
typedef short short4v __attribute__((ext_vector_type(4)));
typedef unsigned short ushort8v __attribute__((ext_vector_type(8)));
typedef float floatx4 __attribute__((ext_vector_type(4)));

__device__ __forceinline__ unsigned short f2bf(float f) {
    unsigned u = __builtin_bit_cast(unsigned, f);
    u += 0x7FFFu + ((u >> 16) & 1u);   // round-to-nearest-even
    return (unsigned short)(u >> 16);
}
__device__ __forceinline__ float bf2f(unsigned short b) {
    unsigned u = ((unsigned)b) << 16;
    return __builtin_bit_cast(float, u);
}

// ---------------------------------------------------------------------------
// PREP: blocks 0..383 build swizzled fused weights; block 384 zeroes norms;
// blocks 385..400 per-batch q contributions (+layer-1 biases), exact fp32.
// wswz: flat = ((ct*12+s)*64 + lane)*8 + j <-> B[k=s*32+(lane>>4)*8+j][n=ct*16+(lane&15)]
// ---------------------------------------------------------------------------
__global__ void prep_kernel(const float* __restrict__ q_embs,
                            const float* __restrict__ coin_w1,
                            const float* __restrict__ coin_b1,
                            const float* __restrict__ path_w1,
                            const float* __restrict__ path_b1,
                            unsigned short* __restrict__ wswz,
                            float* __restrict__ qcoin, float* __restrict__ qpath,
                            float* __restrict__ norms) {
    int blk = blockIdx.x;
    int t = threadIdx.x;
    if (blk < 384) {
        int f = blk * 256 + t;                   // 98304 total
        int j  = f & 7;
        int l  = (f >> 3) & 63;
        int ss = (f >> 9) % KSTEPS;
        int ct = f / (KSTEPS * 512);
        int k = ss * 32 + ((l >> 4) << 3) + j;
        int n = ct * 16 + (l & 15);
        float v = (n < H_SZ) ? coin_w1[k * H_SZ + n]
                             : path_w1[k * H_SZ + (n - H_SZ)];
        wswz[f] = f2bf(v);
    } else if (blk == 384) {
        if (t < B_SZ) norms[t] = 0.f;
    } else {
        int b = blk - 385;
        const float* q = q_embs + b * D_SZ;
        if (t < H_SZ) {
            float acc = coin_b1[t];
            for (int d = 0; d < D_SZ; d++)
                acc += q[d] * coin_w1[(D_SZ + d) * H_SZ + t];
            qcoin[b * H_SZ + t] = acc;
        } else if (t < 2 * H_SZ) {
            int h = t - H_SZ;
            float acc = path_b1[h];
            for (int d = 0; d < D_SZ; d++)
                acc += q[d] * path_w1[(D_SZ + K_SZ + d) * H_SZ + h];
            qpath[b * H_SZ + h] = acc;
        }
    }
}

// ---------------------------------------------------------------------------
// GEMM v3: barrier-free, LDS-free. H[131072 x 256] = sent(bf16) @ Wfused(bf16).
// One 64-row tile per block; wave w owns cols [64w, 64w+64) (4 col-tiles).
// A fragments loaded directly from global fp32 (one full 128B line per row
// per k-step), converted to bf16 in-register. B fragments streamed from the
// pre-swizzled, L2-resident wswz (contiguous 1KB per load instruction).
// Output blocked: hB[mt16*2048 + col*16 + row16], one 8B store per frag.
// ---------------------------------------------------------------------------
__global__ __launch_bounds__(256, 4)
void gemm_fused(const float* __restrict__ sent,
                const unsigned short* __restrict__ wswz,
                unsigned short* __restrict__ hcoinB,
                unsigned short* __restrict__ hpathB) {
    const int tid = threadIdx.x;
    const int wave = tid >> 6, lane = tid & 63;
    const int m_lane = lane & 15, quad = lane >> 4;
    const int mt = blockIdx.x;               // 2048 blocks, one 64-row tile each

    unsigned short* dstbase = (wave < 2) ? hcoinB : hpathB;
    const int colw = (wave & 1) * 64;

    // lane's A base: row = mt*64 + rt*16 + m_lane, k-offset quad*8
    const float* abase = sent + (size_t)mt * 64 * D_SZ + (size_t)m_lane * D_SZ + quad * 8;
    // lane's B base for this wave's first col-tile
    const unsigned short* wbase = wswz + (size_t)wave * 4 * KSTEPS * 512 + lane * 8;

    floatx4 acc[4][4];
#pragma unroll
    for (int rt = 0; rt < 4; rt++)
#pragma unroll
        for (int c = 0; c < 4; c++) acc[rt][c] = (floatx4){0.f, 0.f, 0.f, 0.f};

    for (int s = 0; s < KSTEPS; s++) {
        short8 bf[4];
#pragma unroll
        for (int c = 0; c < 4; c++)
            bf[c] = *(const short8*)(wbase + (size_t)(c * KSTEPS + s) * 512);
#pragma unroll
        for (int rt = 0; rt < 4; rt++) {
            const float* ap = abase + rt * 16 * D_SZ + s * 32;
            float4 a0 = *(const float4*)ap;
            float4 a1 = *(const float4*)(ap + 4);
            short8 af;
            af[0] = (short)f2bf(a0.x); af[1] = (short)f2bf(a0.y);
            af[2] = (short)f2bf(a0.z); af[3] = (short)f2bf(a0.w);
            af[4] = (short)f2bf(a1.x); af[5] = (short)f2bf(a1.y);
            af[6] = (short)f2bf(a1.z); af[7] = (short)f2bf(a1.w);
#pragma unroll
            for (int c = 0; c < 4; c++)
                acc[rt][c] = __builtin_amdgcn_mfma_f32_16x16x32_bf16(af, bf[c], acc[rt][c], 0, 0, 0);
        }
    }

    // epilogue: one 8B store per (rt, col-tile); rows quad*4..+3 contiguous
#pragma unroll
    for (int rt = 0; rt < 4; rt++) {
        int mt16 = mt * 4 + rt;
#pragma unroll
        for (int c = 0; c < 4; c++) {
            int col = colw + c * 16 + m_lane;
            short4v sv;
            sv.x = (short)f2bf(acc[rt][c][0]); sv.y = (short)f2bf(acc[rt][c][1]);
            sv.z = (short)f2bf(acc[rt][c][2]); sv.w = (short)f2bf(acc[rt][c][3]);
            *(short4v*)(dstbase + (size_t)mt16 * 2048 + col * 16 + quad * 4) = sv;
        }
    }
}

// ---------------------------------------------------------------------------
// amps + walk init: amps[m] = relu(hcoin[m]+qcoin[b]) @ w2 + b2 ; z0 = amps/256
// hcoinB blocked: h[m][c] = hcoinB[(m>>4)*2048 + c*16 + (m&15)]
// ---------------------------------------------------------------------------
__global__ __launch_bounds__(256)
void amps_init_kernel(const unsigned short* __restrict__ hcoinB,
                      const float* __restrict__ qcoin,
                      const float* __restrict__ coin_w2,
                      const float* __restrict__ coin_b2,
                      float* __restrict__ amps, float* __restrict__ z0) {
    __shared__ float w2s[H_SZ * K_SZ];
    __shared__ float qcs[H_SZ];
    const int tid = threadIdx.x;
    const int m = blockIdx.x * 256 + tid;
    const int b = (blockIdx.x * 256) >> 13;      // block-uniform
    for (int i = tid; i < H_SZ * K_SZ; i += 256) w2s[i] = coin_w2[i];
    if (tid < H_SZ) qcs[tid] = qcoin[b * H_SZ + tid];
    __syncthreads();

    const unsigned short* hb = hcoinB + (size_t)(m >> 4) * 2048 + (m & 15);
    float acc[K_SZ];
#pragma unroll
    for (int j = 0; j < K_SZ; j++) acc[j] = coin_b2[j];

    for (int h = 0; h < H_SZ; h++) {
        float hv = bf2f(hb[h * 16]) + qcs[h];
        hv = hv > 0.f ? hv : 0.f;
        float4 wa = *(const float4*)&w2s[h * 8];
        float4 wb = *(const float4*)&w2s[h * 8 + 4];
        acc[0] += hv * wa.x; acc[1] += hv * wa.y; acc[2] += hv * wa.z; acc[3] += hv * wa.w;
        acc[4] += hv * wb.x; acc[5] += hv * wb.y; acc[6] += hv * wb.z; acc[7] += hv * wb.w;
    }
    const float c0 = 1.0f / 256.0f;              // 1/sqrt(N*K)
    float4 o0 = {acc[0], acc[1], acc[2], acc[3]};
    float4 o1 = {acc[4], acc[5], acc[6], acc[7]};
    *(float4*)(amps + (size_t)m * 8)     = o0;
    *(float4*)(amps + (size_t)m * 8 + 4) = o1;
    float4 s0 = {acc[0]*c0, acc[1]*c0, acc[2]*c0, acc[3]*c0};
    float4 s1 = {acc[4]*c0, acc[5]*c0, acc[6]*c0, acc[7]*c0};
    *(float4*)(z0 + (size_t)m * 8)     = s0;
    *(float4*)(z0 + (size_t)m * 8 + 4) = s1;
}

// ---------------------------------------------------------------------------
// walk step (un-normalized; intermediate norms cancel algebraically):
//   v = z[m] + sum_valid z[nbr]
//   last==0:  out[m] = v * amps[m]
//   last==1:  out[m] = v ; atomically accumulate ssq into norms[b]
// ---------------------------------------------------------------------------
__global__ __launch_bounds__(256)
void walk_step(const float* __restrict__ z,
               const int* __restrict__ neighbors,
               const float* __restrict__ amps,
               float* __restrict__ outz,
               float* __restrict__ norms, int last) {
    const int g = blockIdx.x * 256 + threadIdx.x;    // 262144 threads
    const int m = g >> 1, half = g & 1;
    const int b = m >> 13;
    const size_t nbase = (size_t)b << 13;
    const int off = half * 4;

    float4 v = *(const float4*)(z + (size_t)m * 8 + off);
    int nbr[KN_SZ];
    const int4* nb4 = (const int4*)(neighbors + (size_t)m * KN_SZ);
#pragma unroll
    for (int i = 0; i < 4; i++) *(int4*)&nbr[i * 4] = nb4[i];
#pragma unroll
    for (int i = 0; i < KN_SZ; i++) {
        int nn = nbr[i];
        if (nn >= 0 && nn < N_SZ) {
            float4 gv = *(const float4*)(z + (nbase + nn) * 8 + off);
            v.x += gv.x; v.y += gv.y; v.z += gv.z; v.w += gv.w;
        }
    }
    if (!last) {
        float4 a = *(const float4*)(amps + (size_t)m * 8 + off);
        v.x *= a.x; v.y *= a.y; v.z *= a.z; v.w *= a.w;
        *(float4*)(outz + (size_t)m * 8 + off) = v;
    } else {
        *(float4*)(outz + (size_t)m * 8 + off) = v;
        float ss = v.x * v.x + v.y * v.y + v.z * v.z + v.w * v.w;
#pragma unroll
        for (int o = 32; o > 0; o >>= 1) ss += __shfl_down(ss, o);
        __shared__ float blocksum;
        if (threadIdx.x == 0) blocksum = 0.f;
        __syncthreads();
        if ((threadIdx.x & 63) == 0) atomicAdd(&blocksum, ss);
        __syncthreads();
        if (threadIdx.x == 0) atomicAdd(&norms[b], blocksum);
    }
}

// ---------------------------------------------------------------------------
// logits[m] = relu(hpath[m] + qpath[b] + state @ w1_state) @ path_w2 + path_b2
// state = u2[m] * rsqrt(norms[b])  (final normalize, guarded)
// ---------------------------------------------------------------------------
__global__ __launch_bounds__(256)
void logits_kernel(const unsigned short* __restrict__ hpathB,
                   const float* __restrict__ qpath,
                   const float* __restrict__ u2,
                   const float* __restrict__ norms,
                   const float* __restrict__ path_w1,
                   const float* __restrict__ path_w2,
                   const float* __restrict__ path_b2,
                   float* __restrict__ out) {
    __shared__ float w1t[H_SZ * K_SZ];   // w1t[h*8+j] = path_w1[(384+j)*128 + h]
    __shared__ float w2s[H_SZ];
    __shared__ float qps[H_SZ];
    const int tid = threadIdx.x;
    const int m = blockIdx.x * 256 + tid;
    const int b = (blockIdx.x * 256) >> 13;      // block-uniform
    for (int i = tid; i < K_SZ * H_SZ; i += 256) {
        int h = i >> 3, j = i & 7;
        w1t[i] = path_w1[(D_SZ + j) * H_SZ + h];
    }
    if (tid < H_SZ) { w2s[tid] = path_w2[tid]; qps[tid] = qpath[b * H_SZ + tid]; }
    __syncthreads();

    float ssq = norms[b];
    float inv = ssq > 0.f ? rsqrtf(ssq) : 1.0f;
    float st[K_SZ];
    {
        float4 s0 = *(const float4*)(u2 + (size_t)m * 8);
        float4 s1 = *(const float4*)(u2 + (size_t)m * 8 + 4);
        st[0] = s0.x * inv; st[1] = s0.y * inv; st[2] = s0.z * inv; st[3] = s0.w * inv;
        st[4] = s1.x * inv; st[5] = s1.y * inv; st[6] = s1.z * inv; st[7] = s1.w * inv;
    }

    const unsigned short* hb = hpathB + (size_t)(m >> 4) * 2048 + (m & 15);
    float acc = path_b2[0];
    for (int h = 0; h < H_SZ; h++) {
        float hv = bf2f(hb[h * 16]) + qps[h];
        float4 wa = *(const float4*)&w1t[h * 8];
        float4 wb = *(const float4*)&w1t[h * 8 + 4];
        hv += st[0]*wa.x + st[1]*wa.y + st[2]*wa.z + st[3]*wa.w
            + st[4]*wb.x + st[5]*wb.y + st[6]*wb.z + st[7]*wb.w;
        hv = hv > 0.f ? hv : 0.f;
        acc += hv * w2s[h];
    }
    out[m] = acc;
}

// ---------------------------------------------------------------------------
extern "C" void kernel_launch(void* const* d_in, const int* in_sizes, int n_in,
                              void* d_out, int out_size, void* d_ws, size_t ws_size,
                              hipStream_t stream) {
    const float* sent      = (const float*)d_in[0];
    const float* q_embs    = (const float*)d_in[1];
    const int*   neighbors = (const int*)d_in[2];
    const float* coin_w1   = (const float*)d_in[3];
    const float* coin_b1   = (const float*)d_in[4];
    const float* coin_w2   = (const float*)d_in[5];
    const float* coin_b2   = (const float*)d_in[6];
    const float* path_w1   = (const float*)d_in[7];
    const float* path_b1   = (const float*)d_in[8];
    const float* path_w2   = (const float*)d_in[9];
    const float* path_b2   = (const float*)d_in[10];
    float* out = (float*)d_out;

    char* ws = (char*)d_ws;
    unsigned short* wswz = (unsigned short*)ws;                   // 196608 B
    float* qcoin = (float*)(ws + 196608);                         // 8192 B
    float* qpath = (float*)(ws + 196608 + 8192);                  // 8192 B
    float* norms = (float*)(ws + 196608 + 16384);                 // 256 B
    unsigned short* hcoinB = (unsigned short*)(ws + 213248);      // 33554432 B
    unsigned short* hpathB = hcoinB + (size_t)M_TOTAL * H_SZ;     // 33554432 B
    float* amps = (float*)(ws + 213248 + 2ull * 33554432ull);     // 4 MB
    float* zA   = amps + (size_t)M_TOTAL * K_SZ;                  // 4 MB
    float* zB   = zA   + (size_t)M_TOTAL * K_SZ;                  // 4 MB

    prep_kernel<<<401, 256, 0, stream>>>(q_embs, coin_w1, coin_b1, path_w1, path_b1,
                                         wswz, qcoin, qpath, norms);
    gemm_fused<<<MT64, 256, 0, stream>>>(sent, wswz, hcoinB, hpathB);
    amps_init_kernel<<<M_TOTAL / 256, 256, 0, stream>>>(hcoinB, qcoin, coin_w2, coin_b2, amps, zA);
    walk_step<<<2 * M_TOTAL / 256, 256, 0, stream>>>(zA, neighbors, amps, zB, norms, 0);
    walk_step<<<2 * M_TOTAL / 256, 256, 0, stream>>>(zB, neighbors, amps, zA, norms, 0);
    walk_step<<<2 * M_TOTAL / 256, 256, 0, stream>>>(zA, neighbors, amps, zB, norms, 1);
    logits_kernel<<<M_TOTAL / 256, 256, 0, stream>>>(hpathB, qpath, zB, norms,
                                                     path_w1, path_w2, path_b2, out);
}

// Round 5
// 415.050 us; speedup vs baseline: 1.1629x; 1.1052x over previous
//
#include <hip/hip_runtime.h>

#define B_SZ 16
#define N_SZ 8192
#define D_SZ 384
#define KN_SZ 16
#define K_SZ 8
#define H_SZ 128
#define M_TOTAL (B_SZ * N_SZ)   // 131072 nodes
#define KSTEPS 12               // 384 / 32
#define MT64 (M_TOTAL / 64)     // 2048 64-row tiles
#define LDSA_STRIDE 400         // bf16 elems; 200 dw == 8 mod 32 -> conflict-free b128

typedef short short8 __attribute__((ext_vector_type(8)));
typedef short short4v __attribute__((ext_vector_type(4)));
typedef float floatx4 __attribute__((ext_vector_type(4)));

__device__ __forceinline__ unsigned short f2bf(float f) {
    unsigned u = __builtin_bit_cast(unsigned, f);
    u += 0x7FFFu + ((u >> 16) & 1u);   // round-to-nearest-even
    return (unsigned short)(u >> 16);
}
__device__ __forceinline__ float bf2f(unsigned short b) {
    unsigned u = ((unsigned)b) << 16;
    return __builtin_bit_cast(float, u);
}

// ---------------------------------------------------------------------------
// PREP: blocks 0..383 build swizzled fused weights; block 384 zeroes norms;
// blocks 385..400 per-batch q contributions (+layer-1 biases), exact fp32.
// wswz: flat = ((ct*12+s)*64 + lane)*8 + j <-> B[k=s*32+(lane>>4)*8+j][n=ct*16+(lane&15)]
// ---------------------------------------------------------------------------
__global__ void prep_kernel(const float* __restrict__ q_embs,
                            const float* __restrict__ coin_w1,
                            const float* __restrict__ coin_b1,
                            const float* __restrict__ path_w1,
                            const float* __restrict__ path_b1,
                            unsigned short* __restrict__ wswz,
                            float* __restrict__ qcoin, float* __restrict__ qpath,
                            float* __restrict__ norms) {
    int blk = blockIdx.x;
    int t = threadIdx.x;
    if (blk < 384) {
        int f = blk * 256 + t;                   // 98304 total
        int j  = f & 7;
        int l  = (f >> 3) & 63;
        int ss = (f >> 9) % KSTEPS;
        int ct = f / (KSTEPS * 512);
        int k = ss * 32 + ((l >> 4) << 3) + j;
        int n = ct * 16 + (l & 15);
        float v = (n < H_SZ) ? coin_w1[k * H_SZ + n]
                             : path_w1[k * H_SZ + (n - H_SZ)];
        wswz[f] = f2bf(v);
    } else if (blk == 384) {
        if (t < B_SZ) norms[t] = 0.f;
    } else {
        int b = blk - 385;
        const float* q = q_embs + b * D_SZ;
        if (t < H_SZ) {
            float acc = coin_b1[t];
            for (int d = 0; d < D_SZ; d++)
                acc += q[d] * coin_w1[(D_SZ + d) * H_SZ + t];
            qcoin[b * H_SZ + t] = acc;
        } else if (t < 2 * H_SZ) {
            int h = t - H_SZ;
            float acc = path_b1[h];
            for (int d = 0; d < D_SZ; d++)
                acc += q[d] * path_w1[(D_SZ + K_SZ + d) * H_SZ + h];
            qpath[b * H_SZ + h] = acc;
        }
    }
}

// ---------------------------------------------------------------------------
// GEMM v4: one 64-row tile per block, ONE barrier, staged LDS.
// Stage: copy-order float4 (24/thread, contiguous 96KB/block) -> bf16 LDS.
// K-loop: ds_read_b128 A-frags (stride 400: conflict-free), B streamed from
// L2-resident pre-swizzled wswz, s-loop fully unrolled.
// Wave w owns cols [64w, 64w+64). Output blocked: hB[mt16*2048+col*16+row16].
// ---------------------------------------------------------------------------
__global__ __launch_bounds__(256)
void gemm_fused(const float* __restrict__ sent,
                const unsigned short* __restrict__ wswz,
                unsigned short* __restrict__ hcoinB,
                unsigned short* __restrict__ hpathB) {
    __shared__ short als[64 * LDSA_STRIDE];      // 51200 B -> 3 blocks/CU
    const int tid = threadIdx.x;
    const int wave = tid >> 6, lane = tid & 63;
    const int m_lane = lane & 15, quad = lane >> 4;
    const int mt = blockIdx.x;                   // 2048 blocks, one tile each

    // ---- stage A: 64 rows x 384 fp32 -> bf16 LDS, copy order ----
    const float* abase = sent + (size_t)mt * 64 * D_SZ;
#pragma unroll
    for (int g = 0; g < 3; g++) {
        float4 v[8];
#pragma unroll
        for (int u = 0; u < 8; u++)
            v[u] = *(const float4*)(abase + (size_t)((g * 8 + u) * 256 + tid) * 4);
#pragma unroll
        for (int u = 0; u < 8; u++) {
            int e4 = (g * 8 + u) * 256 + tid;
            int row = e4 / 96;                   // 96 float4 per row
            int c4  = e4 - row * 96;
            short4v sv;
            sv.x = (short)f2bf(v[u].x); sv.y = (short)f2bf(v[u].y);
            sv.z = (short)f2bf(v[u].z); sv.w = (short)f2bf(v[u].w);
            *(short4v*)&als[row * LDSA_STRIDE + c4 * 4] = sv;
        }
    }
    __syncthreads();                             // the only barrier

    // ---- K-loop ----
    const unsigned short* wbase = wswz + (size_t)wave * 4 * KSTEPS * 512 + lane * 8;
    floatx4 acc[4][4];
#pragma unroll
    for (int rt = 0; rt < 4; rt++)
#pragma unroll
        for (int c = 0; c < 4; c++) acc[rt][c] = (floatx4){0.f, 0.f, 0.f, 0.f};

#pragma unroll
    for (int s = 0; s < KSTEPS; s++) {
        short8 bf[4];
#pragma unroll
        for (int c = 0; c < 4; c++)
            bf[c] = *(const short8*)(wbase + (size_t)(c * KSTEPS + s) * 512);
        short8 af[4];
#pragma unroll
        for (int rt = 0; rt < 4; rt++)
            af[rt] = *(const short8*)&als[(rt * 16 + m_lane) * LDSA_STRIDE + s * 32 + quad * 8];
#pragma unroll
        for (int rt = 0; rt < 4; rt++)
#pragma unroll
            for (int c = 0; c < 4; c++)
                acc[rt][c] = __builtin_amdgcn_mfma_f32_16x16x32_bf16(af[rt], bf[c], acc[rt][c], 0, 0, 0);
    }

    // ---- epilogue: one 8B store per (rt, col-tile) ----
    unsigned short* dstbase = (wave < 2) ? hcoinB : hpathB;
    const int colw = (wave & 1) * 64;
#pragma unroll
    for (int rt = 0; rt < 4; rt++) {
        int mt16 = mt * 4 + rt;
#pragma unroll
        for (int c = 0; c < 4; c++) {
            int col = colw + c * 16 + m_lane;
            short4v sv;
            sv.x = (short)f2bf(acc[rt][c][0]); sv.y = (short)f2bf(acc[rt][c][1]);
            sv.z = (short)f2bf(acc[rt][c][2]); sv.w = (short)f2bf(acc[rt][c][3]);
            *(short4v*)(dstbase + (size_t)mt16 * 2048 + col * 16 + quad * 4) = sv;
        }
    }
}

// ---------------------------------------------------------------------------
// amps + walk init: amps[m] = relu(hcoin[m]+qcoin[b]) @ w2 + b2 ; z0 = amps/256
// hcoinB blocked: h[m][c] = hcoinB[(m>>4)*2048 + c*16 + (m&15)]
// ---------------------------------------------------------------------------
__global__ __launch_bounds__(256)
void amps_init_kernel(const unsigned short* __restrict__ hcoinB,
                      const float* __restrict__ qcoin,
                      const float* __restrict__ coin_w2,
                      const float* __restrict__ coin_b2,
                      float* __restrict__ amps, float* __restrict__ z0) {
    __shared__ float w2s[H_SZ * K_SZ];
    __shared__ float qcs[H_SZ];
    const int tid = threadIdx.x;
    const int m = blockIdx.x * 256 + tid;
    const int b = (blockIdx.x * 256) >> 13;      // block-uniform
    for (int i = tid; i < H_SZ * K_SZ; i += 256) w2s[i] = coin_w2[i];
    if (tid < H_SZ) qcs[tid] = qcoin[b * H_SZ + tid];
    __syncthreads();

    const unsigned short* hb = hcoinB + (size_t)(m >> 4) * 2048 + (m & 15);
    float acc[K_SZ];
#pragma unroll
    for (int j = 0; j < K_SZ; j++) acc[j] = coin_b2[j];

    for (int h = 0; h < H_SZ; h++) {
        float hv = bf2f(hb[h * 16]) + qcs[h];
        hv = hv > 0.f ? hv : 0.f;
        float4 wa = *(const float4*)&w2s[h * 8];
        float4 wb = *(const float4*)&w2s[h * 8 + 4];
        acc[0] += hv * wa.x; acc[1] += hv * wa.y; acc[2] += hv * wa.z; acc[3] += hv * wa.w;
        acc[4] += hv * wb.x; acc[5] += hv * wb.y; acc[6] += hv * wb.z; acc[7] += hv * wb.w;
    }
    const float c0 = 1.0f / 256.0f;              // 1/sqrt(N*K)
    float4 o0 = {acc[0], acc[1], acc[2], acc[3]};
    float4 o1 = {acc[4], acc[5], acc[6], acc[7]};
    *(float4*)(amps + (size_t)m * 8)     = o0;
    *(float4*)(amps + (size_t)m * 8 + 4) = o1;
    float4 s0 = {acc[0]*c0, acc[1]*c0, acc[2]*c0, acc[3]*c0};
    float4 s1 = {acc[4]*c0, acc[5]*c0, acc[6]*c0, acc[7]*c0};
    *(float4*)(z0 + (size_t)m * 8)     = s0;
    *(float4*)(z0 + (size_t)m * 8 + 4) = s1;
}

// ---------------------------------------------------------------------------
// walk step (un-normalized; intermediate norms cancel algebraically):
//   v = z[m] + sum_valid z[nbr]
//   last==0:  out[m] = v * amps[m]
//   last==1:  out[m] = v ; atomically accumulate ssq into norms[b]
// ---------------------------------------------------------------------------
__global__ __launch_bounds__(256)
void walk_step(const float* __restrict__ z,
               const int* __restrict__ neighbors,
               const float* __restrict__ amps,
               float* __restrict__ outz,
               float* __restrict__ norms, int last) {
    const int g = blockIdx.x * 256 + threadIdx.x;    // 262144 threads
    const int m = g >> 1, half = g & 1;
    const int b = m >> 13;
    const size_t nbase = (size_t)b << 13;
    const int off = half * 4;

    float4 v = *(const float4*)(z + (size_t)m * 8 + off);
    int nbr[KN_SZ];
    const int4* nb4 = (const int4*)(neighbors + (size_t)m * KN_SZ);
#pragma unroll
    for (int i = 0; i < 4; i++) *(int4*)&nbr[i * 4] = nb4[i];
#pragma unroll
    for (int i = 0; i < KN_SZ; i++) {
        int nn = nbr[i];
        if (nn >= 0 && nn < N_SZ) {
            float4 gv = *(const float4*)(z + (nbase + nn) * 8 + off);
            v.x += gv.x; v.y += gv.y; v.z += gv.z; v.w += gv.w;
        }
    }
    if (!last) {
        float4 a = *(const float4*)(amps + (size_t)m * 8 + off);
        v.x *= a.x; v.y *= a.y; v.z *= a.z; v.w *= a.w;
        *(float4*)(outz + (size_t)m * 8 + off) = v;
    } else {
        *(float4*)(outz + (size_t)m * 8 + off) = v;
        float ss = v.x * v.x + v.y * v.y + v.z * v.z + v.w * v.w;
#pragma unroll
        for (int o = 32; o > 0; o >>= 1) ss += __shfl_down(ss, o);
        __shared__ float blocksum;
        if (threadIdx.x == 0) blocksum = 0.f;
        __syncthreads();
        if ((threadIdx.x & 63) == 0) atomicAdd(&blocksum, ss);
        __syncthreads();
        if (threadIdx.x == 0) atomicAdd(&norms[b], blocksum);
    }
}

// ---------------------------------------------------------------------------
// logits[m] = relu(hpath[m] + qpath[b] + state @ w1_state) @ path_w2 + path_b2
// state = u2[m] * rsqrt(norms[b])  (final normalize, guarded)
// ---------------------------------------------------------------------------
__global__ __launch_bounds__(256)
void logits_kernel(const unsigned short* __restrict__ hpathB,
                   const float* __restrict__ qpath,
                   const float* __restrict__ u2,
                   const float* __restrict__ norms,
                   const float* __restrict__ path_w1,
                   const float* __restrict__ path_w2,
                   const float* __restrict__ path_b2,
                   float* __restrict__ out) {
    __shared__ float w1t[H_SZ * K_SZ];   // w1t[h*8+j] = path_w1[(384+j)*128 + h]
    __shared__ float w2s[H_SZ];
    __shared__ float qps[H_SZ];
    const int tid = threadIdx.x;
    const int m = blockIdx.x * 256 + tid;
    const int b = (blockIdx.x * 256) >> 13;      // block-uniform
    for (int i = tid; i < K_SZ * H_SZ; i += 256) {
        int h = i >> 3, j = i & 7;
        w1t[i] = path_w1[(D_SZ + j) * H_SZ + h];
    }
    if (tid < H_SZ) { w2s[tid] = path_w2[tid]; qps[tid] = qpath[b * H_SZ + tid]; }
    __syncthreads();

    float ssq = norms[b];
    float inv = ssq > 0.f ? rsqrtf(ssq) : 1.0f;
    float st[K_SZ];
    {
        float4 s0 = *(const float4*)(u2 + (size_t)m * 8);
        float4 s1 = *(const float4*)(u2 + (size_t)m * 8 + 4);
        st[0] = s0.x * inv; st[1] = s0.y * inv; st[2] = s0.z * inv; st[3] = s0.w * inv;
        st[4] = s1.x * inv; st[5] = s1.y * inv; st[6] = s1.z * inv; st[7] = s1.w * inv;
    }

    const unsigned short* hb = hpathB + (size_t)(m >> 4) * 2048 + (m & 15);
    float acc = path_b2[0];
    for (int h = 0; h < H_SZ; h++) {
        float hv = bf2f(hb[h * 16]) + qps[h];
        float4 wa = *(const float4*)&w1t[h * 8];
        float4 wb = *(const float4*)&w1t[h * 8 + 4];
        hv += st[0]*wa.x + st[1]*wa.y + st[2]*wa.z + st[3]*wa.w
            + st[4]*wb.x + st[5]*wb.y + st[6]*wb.z + st[7]*wb.w;
        hv = hv > 0.f ? hv : 0.f;
        acc += hv * w2s[h];
    }
    out[m] = acc;
}

// ---------------------------------------------------------------------------
extern "C" void kernel_launch(void* const* d_in, const int* in_sizes, int n_in,
                              void* d_out, int out_size, void* d_ws, size_t ws_size,
                              hipStream_t stream) {
    const float* sent      = (const float*)d_in[0];
    const float* q_embs    = (const float*)d_in[1];
    const int*   neighbors = (const int*)d_in[2];
    const float* coin_w1   = (const float*)d_in[3];
    const float* coin_b1   = (const float*)d_in[4];
    const float* coin_w2   = (const float*)d_in[5];
    const float* coin_b2   = (const float*)d_in[6];
    const float* path_w1   = (const float*)d_in[7];
    const float* path_b1   = (const float*)d_in[8];
    const float* path_w2   = (const float*)d_in[9];
    const float* path_b2   = (const float*)d_in[10];
    float* out = (float*)d_out;

    char* ws = (char*)d_ws;
    unsigned short* wswz = (unsigned short*)ws;                   // 196608 B
    float* qcoin = (float*)(ws + 196608);                         // 8192 B
    float* qpath = (float*)(ws + 196608 + 8192);                  // 8192 B
    float* norms = (float*)(ws + 196608 + 16384);                 // 256 B
    unsigned short* hcoinB = (unsigned short*)(ws + 213248);      // 33554432 B
    unsigned short* hpathB = hcoinB + (size_t)M_TOTAL * H_SZ;     // 33554432 B
    float* amps = (float*)(ws + 213248 + 2ull * 33554432ull);     // 4 MB
    float* zA   = amps + (size_t)M_TOTAL * K_SZ;                  // 4 MB
    float* zB   = zA   + (size_t)M_TOTAL * K_SZ;                  // 4 MB

    prep_kernel<<<401, 256, 0, stream>>>(q_embs, coin_w1, coin_b1, path_w1, path_b1,
                                         wswz, qcoin, qpath, norms);
    gemm_fused<<<MT64, 256, 0, stream>>>(sent, wswz, hcoinB, hpathB);
    amps_init_kernel<<<M_TOTAL / 256, 256, 0, stream>>>(hcoinB, qcoin, coin_w2, coin_b2, amps, zA);
    walk_step<<<2 * M_TOTAL / 256, 256, 0, stream>>>(zA, neighbors, amps, zB, norms, 0);
    walk_step<<<2 * M_TOTAL / 256, 256, 0, stream>>>(zB, neighbors, amps, zA, norms, 0);
    walk_step<<<2 * M_TOTAL / 256, 256, 0, stream>>>(zA, neighbors, amps, zB, norms, 1);
    logits_kernel<<<M_TOTAL / 256, 256, 0, stream>>>(hpathB, qpath, zB, norms,
                                                     path_w1, path_w2, path_b2, out);
}